// Round 3
// baseline (656.235 us; speedup 1.0000x reference)
//
#include <hip/hip_runtime.h>

#define TTOK   4096
#define DIMK   1024
#define NEXP   8
#define INTERN 1408
#define NPAIRS 8192   // TTOK * TOPK

#define BM  128
#define BN  64
#define BK  32
#define NTH 256
#define MAXRT (NPAIRS / BM + NEXP - 1)   // 71 worst-case row tiles

typedef __attribute__((ext_vector_type(8))) short short8;
typedef __attribute__((ext_vector_type(4))) float f32x4;

#define MFMA16(a, b, c) __builtin_amdgcn_mfma_f32_16x16x32_bf16((a), (b), (c), 0, 0, 0)

__device__ __forceinline__ unsigned short f2bf(float f) {
  unsigned int u = __builtin_bit_cast(unsigned int, f);
  u = (u + 0x7FFFu + ((u >> 16) & 1u)) >> 16;
  return (unsigned short)u;
}
__device__ __forceinline__ float bf2f(unsigned short h) {
  unsigned int u = ((unsigned int)h) << 16;
  return __builtin_bit_cast(float, u);
}
__device__ __forceinline__ void cvt_hl(float f, unsigned short &hi, unsigned short &lo) {
  hi = f2bf(f);
  lo = f2bf(f - bf2f(hi));
}

// async global->LDS, 16B per lane. LDS dest MUST be linear in lane order
// (wave-uniform base + lane*16) — rule #21; tiles below are unpadded flat.
__device__ __forceinline__ void gl_lds16(const void* g, void* l) {
  __builtin_amdgcn_global_load_lds(
      (const __attribute__((address_space(1))) void*)g,
      (__attribute__((address_space(3))) void*)l, 16, 0, 0);
}

// ------------------------------------------- fp32 -> bf16 hi/lo pre-convert ---
__global__ __launch_bounds__(NTH) void convert_kernel(
    const float* __restrict__ src, unsigned short* __restrict__ hi,
    unsigned short* __restrict__ lo, int n4) {
  int i = blockIdx.x * blockDim.x + threadIdx.x;
  const int stride = gridDim.x * blockDim.x;
  for (; i < n4; i += stride) {
    float4 v = reinterpret_cast<const float4*>(src)[i];
    ushort4 h, l;
    cvt_hl(v.x, h.x, l.x); cvt_hl(v.y, h.y, l.y);
    cvt_hl(v.z, h.z, l.z); cvt_hl(v.w, h.w, l.w);
    reinterpret_cast<ushort4*>(hi)[i] = h;
    reinterpret_cast<ushort4*>(lo)[i] = l;
  }
}

// ---------------------------------------------------------------- routing ---
__global__ void route_kernel(const int* __restrict__ w, int* __restrict__ offs,
                             int* __restrict__ pairs) {
  __shared__ int cnt[NEXP], base[NEXP], cur[NEXP], mode;
  const int t = threadIdx.x;
  if (t == 0) mode = 0;
  if (t < NEXP) cnt[t] = 0;
  __syncthreads();
  // width probe: odd 32-bit words all-zero => int64 input (hi words), else int32
  int any = 0;
  for (int i = t; i < NPAIRS / 2; i += NTH) any |= w[2 * i + 1];
  if (any) atomicOr(&mode, 1);
  __syncthreads();
  const int m32 = mode;
  for (int i = t; i < NPAIRS; i += NTH) {
    int e = (m32 ? w[i] : w[2 * i]) & (NEXP - 1);
    atomicAdd(&cnt[e], 1);
  }
  __syncthreads();
  if (t == 0) {
    int s = 0;
    for (int e = 0; e < NEXP; ++e) { base[e] = s; offs[e] = s; s += cnt[e]; }
    offs[NEXP] = s;
  }
  __syncthreads();
  if (t < NEXP) cur[t] = base[t];
  __syncthreads();
  for (int i = t; i < NPAIRS; i += NTH) {
    int e = (m32 ? w[i] : w[2 * i]) & (NEXP - 1);
    int p = atomicAdd(&cur[e], 1);
    pairs[p] = i;   // pair id: token = i>>1, out row = i
  }
}

// ------------------------------------------------------------ tile lookup ---
__device__ __forceinline__ bool find_tile(const int* __restrict__ offs, int rt,
                                          int &e, int &row0, int &row_end) {
  int cum = 0;
  for (int i = 0; i < NEXP; ++i) {
    int b = offs[i], en = offs[i + 1];
    int nt = (en - b + BM - 1) / BM;
    if (rt < cum + nt) { e = i; row0 = b + (rt - cum) * BM; row_end = en; return true; }
    cum += nt;
  }
  return false;
}

// -------------------------------------------------- GEMM1: x @ w1/w3, SiLU ---
__global__ __launch_bounds__(NTH) void gemm1_kernel(
    const unsigned short* __restrict__ xh, const unsigned short* __restrict__ xl,
    const unsigned short* __restrict__ w1h, const unsigned short* __restrict__ w1l,
    const unsigned short* __restrict__ w3h, const unsigned short* __restrict__ w3l,
    const int* __restrict__ offs, const int* __restrict__ pairs,
    unsigned short* __restrict__ h_hi, unsigned short* __restrict__ h_lo) {
  // unpadded flat tiles — required for global_load_lds (linear lane order)
  __shared__ __align__(16) unsigned short Ah[BM * BK], Al[BM * BK];
  __shared__ __align__(16) unsigned short B1h[BN * BK], B1l[BN * BK];
  __shared__ __align__(16) unsigned short B3h[BN * BK], B3l[BN * BK];

  int e, row0, row_end;
  if (!find_tile(offs, (int)blockIdx.x, e, row0, row_end)) return;
  const int n0 = blockIdx.y * BN;
  const int t = threadIdx.x;
  const int ln = t & 63;
  const int wv = t >> 6;          // wave 0..3
  const int fr = ln & 15;         // fragment row/col
  const int fg = ln >> 4;         // k-group
  const int wm = t >> 7;          // 2x2 wave grid over 128x64 output
  const int wn = (t >> 6) & 1;
  const int lr = ln >> 2;         // staging row-within-wave 0..15
  const int lk = (ln & 3) * 8;    // staging k elem offset (16B chunk)

  // staging sources: A rows (gathered tokens), B rows
  int p0 = row0 + wv * 32 + lr;
  int p1 = p0 + 16;
  const int tok0 = ((p0 < row_end) ? pairs[p0] : pairs[row0]) >> 1;
  const int tok1 = ((p1 < row_end) ? pairs[p1] : pairs[row0]) >> 1;
  const size_t a0 = (size_t)tok0 * DIMK + lk;
  const size_t a1 = (size_t)tok1 * DIMK + lk;
  const size_t bB = ((size_t)e * INTERN + n0 + wv * 16 + lr) * DIMK + lk;
  // LDS dest offsets (ushort units), chunk-linear per wave
  const int cA0 = (wv * 128 + ln) * 8;
  const int cA1 = cA0 + 64 * 8;
  const int cB  = (wv * 64 + ln) * 8;

  f32x4 acc1[4][2] = {};
  f32x4 acc3[4][2] = {};

  for (int k0 = 0; k0 < DIMK; k0 += BK) {
    gl_lds16(xh + a0 + k0, Ah + cA0);
    gl_lds16(xh + a1 + k0, Ah + cA1);
    gl_lds16(xl + a0 + k0, Al + cA0);
    gl_lds16(xl + a1 + k0, Al + cA1);
    gl_lds16(w1h + bB + k0, B1h + cB);
    gl_lds16(w1l + bB + k0, B1l + cB);
    gl_lds16(w3h + bB + k0, B3h + cB);
    gl_lds16(w3l + bB + k0, B3l + cB);
    __syncthreads();   // drains vmcnt -> LDS tiles complete

    short8 ah[4], al[4];
#pragma unroll
    for (int m = 0; m < 4; ++m) {
      int ar = (wm * 64 + m * 16 + fr) * BK + fg * 8;
      ah[m] = *reinterpret_cast<const short8*>(&Ah[ar]);
      al[m] = *reinterpret_cast<const short8*>(&Al[ar]);
    }
#pragma unroll
    for (int n = 0; n < 2; ++n) {
      int bc = (wn * 32 + n * 16 + fr) * BK + fg * 8;
      short8 b1h = *reinterpret_cast<const short8*>(&B1h[bc]);
      short8 b1l = *reinterpret_cast<const short8*>(&B1l[bc]);
      short8 b3h = *reinterpret_cast<const short8*>(&B3h[bc]);
      short8 b3l = *reinterpret_cast<const short8*>(&B3l[bc]);
#pragma unroll
      for (int m = 0; m < 4; ++m) {
        acc1[m][n] = MFMA16(ah[m], b1h, acc1[m][n]);
        acc1[m][n] = MFMA16(ah[m], b1l, acc1[m][n]);
        acc1[m][n] = MFMA16(al[m], b1h, acc1[m][n]);
        acc3[m][n] = MFMA16(ah[m], b3h, acc3[m][n]);
        acc3[m][n] = MFMA16(ah[m], b3l, acc3[m][n]);
        acc3[m][n] = MFMA16(al[m], b3h, acc3[m][n]);
      }
    }
    __syncthreads();   // protect tiles from next iteration's staging
  }

  // ---- epilogue: h = silu(x1) * x3, store bf16 hi/lo ----
#pragma unroll
  for (int m = 0; m < 4; ++m)
#pragma unroll
    for (int n = 0; n < 2; ++n)
#pragma unroll
      for (int r = 0; r < 4; ++r) {
        int p = row0 + wm * 64 + m * 16 + fg * 4 + r;
        if (p < row_end) {
          int col = n0 + wn * 32 + n * 16 + fr;
          float x1v = acc1[m][n][r], x3v = acc3[m][n][r];
          float hv = (x1v / (1.0f + __expf(-x1v))) * x3v;
          unsigned short hh, hl;
          cvt_hl(hv, hh, hl);
          size_t o = (size_t)p * INTERN + col;
          h_hi[o] = hh; h_lo[o] = hl;
        }
      }
}

// ----------------------------------------------------- GEMM2: h @ w2, out ---
__global__ __launch_bounds__(NTH) void gemm2_kernel(
    const unsigned short* __restrict__ w2h, const unsigned short* __restrict__ w2l,
    const int* __restrict__ offs, const int* __restrict__ pairs,
    const unsigned short* __restrict__ h_hi, const unsigned short* __restrict__ h_lo,
    float* __restrict__ out) {
  __shared__ __align__(16) unsigned short Ah[BM * BK], Al[BM * BK];
  __shared__ __align__(16) unsigned short Bh[BN * BK], Bl[BN * BK];

  int e, row0, row_end;
  if (!find_tile(offs, (int)blockIdx.x, e, row0, row_end)) return;
  const int n0 = blockIdx.y * BN;
  const int t = threadIdx.x;
  const int ln = t & 63;
  const int wv = t >> 6;
  const int fr = ln & 15;
  const int fg = ln >> 4;
  const int wm = t >> 7;
  const int wn = (t >> 6) & 1;
  const int lr = ln >> 2;
  const int lk = (ln & 3) * 8;

  int p0 = row0 + wv * 32 + lr;
  int p1 = p0 + 16;
  const int ar0 = (p0 < row_end) ? p0 : row0;
  const int ar1 = (p1 < row_end) ? p1 : row0;
  const size_t a0 = (size_t)ar0 * INTERN + lk;
  const size_t a1 = (size_t)ar1 * INTERN + lk;
  const size_t bB = ((size_t)e * DIMK + n0 + wv * 16 + lr) * INTERN + lk;
  const int cA0 = (wv * 128 + ln) * 8;
  const int cA1 = cA0 + 64 * 8;
  const int cB  = (wv * 64 + ln) * 8;

  f32x4 acc[4][2] = {};

  for (int k0 = 0; k0 < INTERN; k0 += BK) {
    gl_lds16(h_hi + a0 + k0, Ah + cA0);
    gl_lds16(h_hi + a1 + k0, Ah + cA1);
    gl_lds16(h_lo + a0 + k0, Al + cA0);
    gl_lds16(h_lo + a1 + k0, Al + cA1);
    gl_lds16(w2h + bB + k0, Bh + cB);
    gl_lds16(w2l + bB + k0, Bl + cB);
    __syncthreads();

    short8 ah[4], al[4];
#pragma unroll
    for (int m = 0; m < 4; ++m) {
      int ar = (wm * 64 + m * 16 + fr) * BK + fg * 8;
      ah[m] = *reinterpret_cast<const short8*>(&Ah[ar]);
      al[m] = *reinterpret_cast<const short8*>(&Al[ar]);
    }
#pragma unroll
    for (int n = 0; n < 2; ++n) {
      int bc = (wn * 32 + n * 16 + fr) * BK + fg * 8;
      short8 bh = *reinterpret_cast<const short8*>(&Bh[bc]);
      short8 bl = *reinterpret_cast<const short8*>(&Bl[bc]);
#pragma unroll
      for (int m = 0; m < 4; ++m) {
        acc[m][n] = MFMA16(ah[m], bh, acc[m][n]);
        acc[m][n] = MFMA16(ah[m], bl, acc[m][n]);
        acc[m][n] = MFMA16(al[m], bh, acc[m][n]);
      }
    }
    __syncthreads();
  }

#pragma unroll
  for (int m = 0; m < 4; ++m)
#pragma unroll
    for (int n = 0; n < 2; ++n)
#pragma unroll
      for (int r = 0; r < 4; ++r) {
        int p = row0 + wm * 64 + m * 16 + fg * 4 + r;
        if (p < row_end) {
          int orow = pairs[p];
          out[(size_t)orow * DIMK + n0 + wn * 32 + n * 16 + fr] = acc[m][n][r];
        }
      }
}

// ------------------------------------------------------------------ launch ---
extern "C" void kernel_launch(void* const* d_in, const int* in_sizes, int n_in,
                              void* d_out, int out_size, void* d_ws, size_t ws_size,
                              hipStream_t stream) {
  const float* x  = (const float*)d_in[0];
  const int*   ei = (const int*)d_in[1];
  const float* w1 = (const float*)d_in[2];
  const float* w2 = (const float*)d_in[3];
  const float* w3 = (const float*)d_in[4];
  float* out = (float*)d_out;

  char* ws = (char*)d_ws;
  int* offs  = (int*)ws;                       // 9 ints
  int* pairs = (int*)(ws + 256);               // 8192 ints

  // bf16 hi/lo pre-converted arrays (~201 MB total incl. h)
  const size_t sz_x = (size_t)TTOK * DIMK;
  const size_t sz_w = (size_t)NEXP * INTERN * DIMK;
  const size_t sz_h = (size_t)NPAIRS * INTERN;
  size_t off = 65536;
  unsigned short* x_hi  = (unsigned short*)(ws + off); off += sz_x * 2;
  unsigned short* x_lo  = (unsigned short*)(ws + off); off += sz_x * 2;
  unsigned short* w1_hi = (unsigned short*)(ws + off); off += sz_w * 2;
  unsigned short* w1_lo = (unsigned short*)(ws + off); off += sz_w * 2;
  unsigned short* w3_hi = (unsigned short*)(ws + off); off += sz_w * 2;
  unsigned short* w3_lo = (unsigned short*)(ws + off); off += sz_w * 2;
  unsigned short* w2_hi = (unsigned short*)(ws + off); off += sz_w * 2;
  unsigned short* w2_lo = (unsigned short*)(ws + off); off += sz_w * 2;
  unsigned short* h_hi  = (unsigned short*)(ws + off); off += sz_h * 2;
  unsigned short* h_lo  = (unsigned short*)(ws + off);

  route_kernel<<<1, NTH, 0, stream>>>(ei, offs, pairs);
  convert_kernel<<<2048, NTH, 0, stream>>>(x,  x_hi,  x_lo,  (int)(sz_x / 4));
  convert_kernel<<<2048, NTH, 0, stream>>>(w1, w1_hi, w1_lo, (int)(sz_w / 4));
  convert_kernel<<<2048, NTH, 0, stream>>>(w3, w3_hi, w3_lo, (int)(sz_w / 4));
  convert_kernel<<<2048, NTH, 0, stream>>>(w2, w2_hi, w2_lo, (int)(sz_w / 4));
  gemm1_kernel<<<dim3(MAXRT, INTERN / BN), NTH, 0, stream>>>(
      x_hi, x_lo, w1_hi, w1_lo, w3_hi, w3_lo, offs, pairs, h_hi, h_lo);
  gemm2_kernel<<<dim3(MAXRT, DIMK / BN), NTH, 0, stream>>>(
      w2_hi, w2_lo, offs, pairs, h_hi, h_lo, out);
}

// Round 8
// 312.706 us; speedup vs baseline: 2.0986x; 2.0986x over previous
//
#include <hip/hip_runtime.h>

#define TTOK   4096
#define DIMK   1024
#define NEXP   8
#define INTERN 1408
#define NPAIRS 8192   // TTOK * TOPK

#define BM  128
#define BN  128
#define BK  64
#define NTH 256
#define MAXRT (NPAIRS / BM + NEXP - 1)   // 71 worst-case row tiles
#define NT1  (INTERN / BN)               // 11 n-tiles gemm1
#define NT2  (DIMK / BN)                 // 8 n-tiles gemm2

typedef __attribute__((ext_vector_type(8))) _Float16 half8;
typedef __attribute__((ext_vector_type(4))) float f32x4;

#define MFMAF16(a, b, c) __builtin_amdgcn_mfma_f32_16x16x32_f16((a), (b), (c), 0, 0, 0)

// async global->LDS, 16B/lane. LDS dest = wave-uniform base + lane*16 (linear);
// swizzle lives in the per-lane GLOBAL source address (m173 pattern).
__device__ __forceinline__ void gl_lds16(const void* g, void* l) {
  __builtin_amdgcn_global_load_lds(
      (const __attribute__((address_space(1))) void*)g,
      (__attribute__((address_space(3))) void*)l, 16, 0, 0);
}

// bijective XCD chunk swizzle (m204): consecutive HW blockIdx round-robin over
// 8 XCDs; this gives each XCD a contiguous chunk of logical tile space.
__device__ __forceinline__ int xcd_swz(int orig, int G) {
  int q = G >> 3, r = G & 7, x = orig & 7, p = orig >> 3;
  return (x < r ? x * (q + 1) : r * (q + 1) + (x - r) * q) + p;
}

// ------------------------------------------------- fp32 -> fp16 pre-convert ---
__global__ __launch_bounds__(NTH) void convert_kernel(
    const float* __restrict__ src, unsigned short* __restrict__ dst, int n4) {
  int i = blockIdx.x * blockDim.x + threadIdx.x;
  const int stride = gridDim.x * blockDim.x;
  for (; i < n4; i += stride) {
    float4 v = reinterpret_cast<const float4*>(src)[i];
    ushort4 o;
    o.x = __builtin_bit_cast(unsigned short, (_Float16)v.x);
    o.y = __builtin_bit_cast(unsigned short, (_Float16)v.y);
    o.z = __builtin_bit_cast(unsigned short, (_Float16)v.z);
    o.w = __builtin_bit_cast(unsigned short, (_Float16)v.w);
    reinterpret_cast<ushort4*>(dst)[i] = o;
  }
}

// ---------------------------------------------------------------- routing ---
__global__ void route_kernel(const int* __restrict__ w, int* __restrict__ offs,
                             int* __restrict__ pairs) {
  __shared__ int cnt[NEXP], base[NEXP], cur[NEXP], mode;
  const int t = threadIdx.x;
  if (t == 0) mode = 0;
  if (t < NEXP) cnt[t] = 0;
  __syncthreads();
  // width probe: odd 32-bit words all-zero => int64 input (hi words), else int32
  int any = 0;
  for (int i = t; i < NPAIRS / 2; i += NTH) any |= w[2 * i + 1];
  if (any) atomicOr(&mode, 1);
  __syncthreads();
  const int m32 = mode;
  for (int i = t; i < NPAIRS; i += NTH) {
    int e = (m32 ? w[i] : w[2 * i]) & (NEXP - 1);
    atomicAdd(&cnt[e], 1);
  }
  __syncthreads();
  if (t == 0) {
    int s = 0;
    for (int e = 0; e < NEXP; ++e) { base[e] = s; offs[e] = s; s += cnt[e]; }
    offs[NEXP] = s;
  }
  __syncthreads();
  if (t < NEXP) cur[t] = base[t];
  __syncthreads();
  for (int i = t; i < NPAIRS; i += NTH) {
    int e = (m32 ? w[i] : w[2 * i]) & (NEXP - 1);
    int p = atomicAdd(&cur[e], 1);
    pairs[p] = i;   // pair id: token = i>>1, out row = i
  }
}

// ------------------------------------------------------------ tile lookup ---
__device__ __forceinline__ bool find_tile(const int* __restrict__ offs, int rt,
                                          int &e, int &row0, int &row_end) {
  int cum = 0;
  for (int i = 0; i < NEXP; ++i) {
    int b = offs[i], en = offs[i + 1];
    int nt = (en - b + BM - 1) / BM;
    if (rt < cum + nt) { e = i; row0 = b + (rt - cum) * BM; row_end = en; return true; }
    cum += nt;
  }
  return false;
}

// -------------------------------------------------- GEMM1: x @ w1/w3, SiLU ---
__global__ __launch_bounds__(NTH, 2) void gemm1_kernel(
    const unsigned short* __restrict__ xf, const unsigned short* __restrict__ w1f,
    const unsigned short* __restrict__ w3f, const int* __restrict__ offs,
    const int* __restrict__ pairs, unsigned short* __restrict__ hf) {
  // flat [row][BK] fp16 tiles, 16KB each. LDS layout: row r chunk c holds
  // global chunk c^(r&7)  (pre-swizzled source, swizzled read — conflict-free)
  __shared__ __align__(16) unsigned short At[BM * BK];
  __shared__ __align__(16) unsigned short B1t[BN * BK];
  __shared__ __align__(16) unsigned short B3t[BN * BK];

  const int lid = xcd_swz((int)blockIdx.x, MAXRT * NT1);
  const int rt = lid % MAXRT, nt = lid / MAXRT;   // rt fastest: XCD sweeps row
                                                  // tiles against L2-hot W slice
  int e, row0, row_end;
  if (!find_tile(offs, rt, e, row0, row_end)) return;
  const int n0 = nt * BN;
  const int t = threadIdx.x;
  const int ln = t & 63;
  const int wv = t >> 6;
  const int wm = wv >> 1, wn = wv & 1;   // 2x2 waves over 128x128 out
  const int fr = ln & 15, fg = ln >> 4;
  const int sr = ln >> 3, sc = ln & 7;   // staging row-in-8 / chunk
  const int sw = (sc ^ sr) * 8;          // swizzled source chunk offset (halfs)

  size_t aA[4], aB[4];
#pragma unroll
  for (int c = 0; c < 4; ++c) {
    int row = wv * 32 + c * 8 + sr;
    int p = row0 + row;
    int tok = ((p < row_end) ? pairs[p] : pairs[row0]) >> 1;
    aA[c] = (size_t)tok * DIMK + sw;
    aB[c] = ((size_t)e * INTERN + n0 + row) * DIMK + sw;
  }

  f32x4 acc1[4][4] = {};
  f32x4 acc3[4][4] = {};

  for (int k0 = 0; k0 < DIMK; k0 += BK) {
#pragma unroll
    for (int c = 0; c < 4; ++c)
      gl_lds16(xf + aA[c] + k0, &At[(wv * 32 + c * 8) * BK]);
#pragma unroll
    for (int c = 0; c < 4; ++c)
      gl_lds16(w1f + aB[c] + k0, &B1t[(wv * 32 + c * 8) * BK]);
#pragma unroll
    for (int c = 0; c < 4; ++c)
      gl_lds16(w3f + aB[c] + k0, &B3t[(wv * 32 + c * 8) * BK]);
    __syncthreads();   // compiler drains vmcnt before s_barrier

#pragma unroll
    for (int kk = 0; kk < 2; ++kk) {
      half8 ah[4];
#pragma unroll
      for (int m = 0; m < 4; ++m) {
        int row = wm * 64 + m * 16 + fr;
        ah[m] = *reinterpret_cast<const half8*>(
            &At[row * BK + (((kk * 4 + fg) ^ (fr & 7)) * 8)]);
      }
#pragma unroll
      for (int n = 0; n < 4; ++n) {
        int row = wn * 64 + n * 16 + fr;
        int bo = row * BK + (((kk * 4 + fg) ^ (fr & 7)) * 8);
        half8 b1 = *reinterpret_cast<const half8*>(&B1t[bo]);
        half8 b3 = *reinterpret_cast<const half8*>(&B3t[bo]);
#pragma unroll
        for (int m = 0; m < 4; ++m) {
          acc1[m][n] = MFMAF16(ah[m], b1, acc1[m][n]);
          acc3[m][n] = MFMAF16(ah[m], b3, acc3[m][n]);
        }
      }
    }
    __syncthreads();
  }

  // ---- epilogue: h = silu(x1) * x3 -> fp16 ----
#pragma unroll
  for (int m = 0; m < 4; ++m)
#pragma unroll
    for (int n = 0; n < 4; ++n)
#pragma unroll
      for (int r = 0; r < 4; ++r) {
        int p = row0 + wm * 64 + m * 16 + fg * 4 + r;
        if (p < row_end) {
          int col = n0 + wn * 64 + n * 16 + fr;
          float a1 = acc1[m][n][r], a3 = acc3[m][n][r];
          float hv = (a1 / (1.0f + __expf(-a1))) * a3;
          hf[(size_t)p * INTERN + col] =
              __builtin_bit_cast(unsigned short, (_Float16)hv);
        }
      }
}

// ----------------------------------------------------- GEMM2: h @ w2, out ---
__global__ __launch_bounds__(NTH, 2) void gemm2_kernel(
    const unsigned short* __restrict__ w2f, const int* __restrict__ offs,
    const int* __restrict__ pairs, const unsigned short* __restrict__ hf,
    float* __restrict__ out) {
  __shared__ __align__(16) unsigned short At[BM * BK];
  __shared__ __align__(16) unsigned short Bt[BN * BK];

  const int lid = xcd_swz((int)blockIdx.x, MAXRT * NT2);
  const int rt = lid % MAXRT, nt = lid / MAXRT;
  int e, row0, row_end;
  if (!find_tile(offs, rt, e, row0, row_end)) return;
  const int n0 = nt * BN;
  const int t = threadIdx.x;
  const int ln = t & 63;
  const int wv = t >> 6;
  const int wm = wv >> 1, wn = wv & 1;
  const int fr = ln & 15, fg = ln >> 4;
  const int sr = ln >> 3, sc = ln & 7;
  const int sw = (sc ^ sr) * 8;

  size_t aA[4], aB[4];
#pragma unroll
  for (int c = 0; c < 4; ++c) {
    int row = wv * 32 + c * 8 + sr;
    int p = row0 + row;
    int ar = (p < row_end) ? p : row0;
    aA[c] = (size_t)ar * INTERN + sw;
    aB[c] = ((size_t)e * DIMK + n0 + row) * INTERN + sw;
  }

  f32x4 acc[4][4] = {};

  for (int k0 = 0; k0 < INTERN; k0 += BK) {
#pragma unroll
    for (int c = 0; c < 4; ++c)
      gl_lds16(hf + aA[c] + k0, &At[(wv * 32 + c * 8) * BK]);
#pragma unroll
    for (int c = 0; c < 4; ++c)
      gl_lds16(w2f + aB[c] + k0, &Bt[(wv * 32 + c * 8) * BK]);
    __syncthreads();

#pragma unroll
    for (int kk = 0; kk < 2; ++kk) {
      half8 ah[4];
#pragma unroll
      for (int m = 0; m < 4; ++m) {
        int row = wm * 64 + m * 16 + fr;
        ah[m] = *reinterpret_cast<const half8*>(
            &At[row * BK + (((kk * 4 + fg) ^ (fr & 7)) * 8)]);
      }
#pragma unroll
      for (int n = 0; n < 4; ++n) {
        int row = wn * 64 + n * 16 + fr;
        half8 b = *reinterpret_cast<const half8*>(
            &Bt[row * BK + (((kk * 4 + fg) ^ (fr & 7)) * 8)]);
#pragma unroll
        for (int m = 0; m < 4; ++m)
          acc[m][n] = MFMAF16(ah[m], b, acc[m][n]);
      }
    }
    __syncthreads();
  }

#pragma unroll
  for (int m = 0; m < 4; ++m)
#pragma unroll
    for (int n = 0; n < 4; ++n)
#pragma unroll
      for (int r = 0; r < 4; ++r) {
        int p = row0 + wm * 64 + m * 16 + fg * 4 + r;
        if (p < row_end) {
          int orow = pairs[p];
          out[(size_t)orow * DIMK + n0 + wn * 64 + n * 16 + fr] = acc[m][n][r];
        }
      }
}

// ------------------------------------------------------------------ launch ---
extern "C" void kernel_launch(void* const* d_in, const int* in_sizes, int n_in,
                              void* d_out, int out_size, void* d_ws, size_t ws_size,
                              hipStream_t stream) {
  const float* x  = (const float*)d_in[0];
  const int*   ei = (const int*)d_in[1];
  const float* w1 = (const float*)d_in[2];
  const float* w2 = (const float*)d_in[3];
  const float* w3 = (const float*)d_in[4];
  float* out = (float*)d_out;

  char* ws = (char*)d_ws;
  int* offs  = (int*)ws;                       // 9 ints
  int* pairs = (int*)(ws + 256);               // 8192 ints

  const size_t sz_x = (size_t)TTOK * DIMK;           // 4.19M
  const size_t sz_w = (size_t)NEXP * INTERN * DIMK;  // 11.53M
  const size_t sz_h = (size_t)NPAIRS * INTERN;       // 11.53M
  size_t off = 65536;
  unsigned short* x_f  = (unsigned short*)(ws + off); off += sz_x * 2;
  unsigned short* w1_f = (unsigned short*)(ws + off); off += sz_w * 2;
  unsigned short* w3_f = (unsigned short*)(ws + off); off += sz_w * 2;
  unsigned short* w2_f = (unsigned short*)(ws + off); off += sz_w * 2;
  unsigned short* h_f  = (unsigned short*)(ws + off);   // ~101 MB total

  route_kernel<<<1, NTH, 0, stream>>>(ei, offs, pairs);
  convert_kernel<<<2048, NTH, 0, stream>>>(x,  x_f,  (int)(sz_x / 4));
  convert_kernel<<<2048, NTH, 0, stream>>>(w1, w1_f, (int)(sz_w / 4));
  convert_kernel<<<2048, NTH, 0, stream>>>(w3, w3_f, (int)(sz_w / 4));
  convert_kernel<<<2048, NTH, 0, stream>>>(w2, w2_f, (int)(sz_w / 4));
  gemm1_kernel<<<MAXRT * NT1, NTH, 0, stream>>>(x_f, w1_f, w3_f, offs, pairs, h_f);
  gemm2_kernel<<<MAXRT * NT2, NTH, 0, stream>>>(w2_f, offs, pairs, h_f, out);
}

// Round 9
// 307.161 us; speedup vs baseline: 2.1365x; 1.0181x over previous
//
#include <hip/hip_runtime.h>

#define TTOK   4096
#define DIMK   1024
#define NEXP   8
#define INTERN 1408
#define NPAIRS 8192   // TTOK * TOPK

#define BM  128
#define BN  128
#define BK  64
#define NTH 256       // route/convert block size
#define NTG 512       // GEMM block size: 8 waves, 2x4 wave grid
#define MAXRT (NPAIRS / BM + NEXP - 1)   // 71 worst-case row tiles
#define NT1  (INTERN / BN)               // 11 n-tiles gemm1
#define NT2  (DIMK / BN)                 // 8 n-tiles gemm2

typedef __attribute__((ext_vector_type(8))) _Float16 half8;
typedef __attribute__((ext_vector_type(4))) float f32x4;

#define MFMAF16(a, b, c) __builtin_amdgcn_mfma_f32_16x16x32_f16((a), (b), (c), 0, 0, 0)

// async global->LDS, 16B/lane. LDS dest = wave-uniform base + lane*16 (linear);
// swizzle lives in the per-lane GLOBAL source address (m173 pattern).
__device__ __forceinline__ void gl_lds16(const void* g, void* l) {
  __builtin_amdgcn_global_load_lds(
      (const __attribute__((address_space(1))) void*)g,
      (__attribute__((address_space(3))) void*)l, 16, 0, 0);
}

// bijective XCD chunk swizzle (m204)
__device__ __forceinline__ int xcd_swz(int orig, int G) {
  int q = G >> 3, r = G & 7, x = orig & 7, p = orig >> 3;
  return (x < r ? x * (q + 1) : r * (q + 1) + (x - r) * q) + p;
}

// --------------------------- fused fp32 -> fp16 pre-convert (all 4 arrays) ---
#define N4X (TTOK * DIMK / 4)
#define N4W (NEXP * INTERN * DIMK / 4)
__global__ __launch_bounds__(NTH) void convert_all_kernel(
    const float* __restrict__ x, const float* __restrict__ w1,
    const float* __restrict__ w3, const float* __restrict__ w2,
    unsigned short* __restrict__ xf, unsigned short* __restrict__ w1f,
    unsigned short* __restrict__ w3f, unsigned short* __restrict__ w2f) {
  const int total = N4X + 3 * N4W;
  int i = blockIdx.x * blockDim.x + threadIdx.x;
  const int stride = gridDim.x * blockDim.x;
  for (; i < total; i += stride) {
    const float* src; unsigned short* dst; int j;
    if (i < N4X) { src = x; dst = xf; j = i; }
    else if (i < N4X + N4W) { src = w1; dst = w1f; j = i - N4X; }
    else if (i < N4X + 2 * N4W) { src = w3; dst = w3f; j = i - N4X - N4W; }
    else { src = w2; dst = w2f; j = i - N4X - 2 * N4W; }
    float4 v = reinterpret_cast<const float4*>(src)[j];
    ushort4 o;
    o.x = __builtin_bit_cast(unsigned short, (_Float16)v.x);
    o.y = __builtin_bit_cast(unsigned short, (_Float16)v.y);
    o.z = __builtin_bit_cast(unsigned short, (_Float16)v.z);
    o.w = __builtin_bit_cast(unsigned short, (_Float16)v.w);
    reinterpret_cast<ushort4*>(dst)[j] = o;
  }
}

// ---------------------------------------------------------------- routing ---
__global__ void route_kernel(const int* __restrict__ w, int* __restrict__ offs,
                             int* __restrict__ pairs) {
  __shared__ int cnt[NEXP], base[NEXP], cur[NEXP], mode;
  const int t = threadIdx.x;
  if (t == 0) mode = 0;
  if (t < NEXP) cnt[t] = 0;
  __syncthreads();
  // width probe: odd 32-bit words all-zero => int64 input (hi words), else int32
  int any = 0;
  for (int i = t; i < NPAIRS / 2; i += NTH) any |= w[2 * i + 1];
  if (any) atomicOr(&mode, 1);
  __syncthreads();
  const int m32 = mode;
  for (int i = t; i < NPAIRS; i += NTH) {
    int e = (m32 ? w[i] : w[2 * i]) & (NEXP - 1);
    atomicAdd(&cnt[e], 1);
  }
  __syncthreads();
  if (t == 0) {
    int s = 0;
    for (int e = 0; e < NEXP; ++e) { base[e] = s; offs[e] = s; s += cnt[e]; }
    offs[NEXP] = s;
  }
  __syncthreads();
  if (t < NEXP) cur[t] = base[t];
  __syncthreads();
  for (int i = t; i < NPAIRS; i += NTH) {
    int e = (m32 ? w[i] : w[2 * i]) & (NEXP - 1);
    int p = atomicAdd(&cur[e], 1);
    pairs[p] = i;   // pair id: token = i>>1, out row = i
  }
}

// ------------------------------------------------------------ tile lookup ---
__device__ __forceinline__ bool find_tile(const int* __restrict__ offs, int rt,
                                          int &e, int &row0, int &row_end) {
  int cum = 0;
  for (int i = 0; i < NEXP; ++i) {
    int b = offs[i], en = offs[i + 1];
    int nt = (en - b + BM - 1) / BM;
    if (rt < cum + nt) { e = i; row0 = b + (rt - cum) * BM; row_end = en; return true; }
    cum += nt;
  }
  return false;
}

// -------------------------------------------------- GEMM1: x @ w1/w3, SiLU ---
// 512 threads = 8 waves as 2(wm) x 4(wn); per wave 64x32 out per matrix.
// acc = 2 matrices * 4x2 f32x4 = 64 regs/lane (was 128 @ 256 thr) -> 2 blocks/CU.
__global__ __launch_bounds__(NTG, 4) void gemm1_kernel(
    const unsigned short* __restrict__ xf, const unsigned short* __restrict__ w1f,
    const unsigned short* __restrict__ w3f, const int* __restrict__ offs,
    const int* __restrict__ pairs, unsigned short* __restrict__ hf) {
  // flat [row][BK] fp16 tiles, 16KB each. LDS row r chunk c holds global
  // chunk c^(r&7) (pre-swizzled source, swizzled read -> 0 bank conflicts, R8-verified)
  __shared__ __align__(16) unsigned short At[BM * BK];
  __shared__ __align__(16) unsigned short B1t[BN * BK];
  __shared__ __align__(16) unsigned short B3t[BN * BK];

  const int lid = xcd_swz((int)blockIdx.x, MAXRT * NT1);
  const int rt = lid % MAXRT, nt = lid / MAXRT;   // rt fastest: XCD sweeps row
  int e, row0, row_end;                           // tiles vs L2-hot W slice
  if (!find_tile(offs, rt, e, row0, row_end)) return;
  const int n0 = nt * BN;
  const int t = threadIdx.x;
  const int ln = t & 63;
  const int wv = t >> 6;                 // wave 0..7
  const int wm = wv >> 2, wn = wv & 3;   // 2x4 wave grid over 128x128 out
  const int fr = ln & 15, fg = ln >> 4;
  const int sr = ln >> 3, sc = ln & 7;   // staging row-in-8 / chunk
  const int sw = (sc ^ sr) * 8;          // swizzled source chunk offset (halfs)

  size_t aA[2], aB[2];
#pragma unroll
  for (int c = 0; c < 2; ++c) {
    int row = wv * 16 + c * 8 + sr;      // 0..127
    int p = row0 + row;
    int tok = ((p < row_end) ? pairs[p] : pairs[row0]) >> 1;
    aA[c] = (size_t)tok * DIMK + sw;
    aB[c] = ((size_t)e * INTERN + n0 + row) * DIMK + sw;
  }

  f32x4 acc1[4][2] = {};
  f32x4 acc3[4][2] = {};

  for (int k0 = 0; k0 < DIMK; k0 += BK) {
#pragma unroll
    for (int c = 0; c < 2; ++c)
      gl_lds16(xf + aA[c] + k0, &At[(wv * 16 + c * 8) * BK]);
#pragma unroll
    for (int c = 0; c < 2; ++c)
      gl_lds16(w1f + aB[c] + k0, &B1t[(wv * 16 + c * 8) * BK]);
#pragma unroll
    for (int c = 0; c < 2; ++c)
      gl_lds16(w3f + aB[c] + k0, &B3t[(wv * 16 + c * 8) * BK]);
    __syncthreads();   // compiler drains vmcnt before s_barrier

#pragma unroll
    for (int kk = 0; kk < 2; ++kk) {
      half8 ah[4];
#pragma unroll
      for (int m = 0; m < 4; ++m) {
        int row = wm * 64 + m * 16 + fr;
        ah[m] = *reinterpret_cast<const half8*>(
            &At[row * BK + (((kk * 4 + fg) ^ (fr & 7)) * 8)]);
      }
#pragma unroll
      for (int n = 0; n < 2; ++n) {
        int row = wn * 32 + n * 16 + fr;
        int bo = row * BK + (((kk * 4 + fg) ^ (fr & 7)) * 8);
        half8 b1 = *reinterpret_cast<const half8*>(&B1t[bo]);
        half8 b3 = *reinterpret_cast<const half8*>(&B3t[bo]);
#pragma unroll
        for (int m = 0; m < 4; ++m) {
          acc1[m][n] = MFMAF16(ah[m], b1, acc1[m][n]);
          acc3[m][n] = MFMAF16(ah[m], b3, acc3[m][n]);
        }
      }
    }
    __syncthreads();
  }

  // ---- epilogue: h = silu(x1) * x3 -> fp16 ----
#pragma unroll
  for (int m = 0; m < 4; ++m)
#pragma unroll
    for (int n = 0; n < 2; ++n)
#pragma unroll
      for (int r = 0; r < 4; ++r) {
        int p = row0 + wm * 64 + m * 16 + fg * 4 + r;
        if (p < row_end) {
          int col = n0 + wn * 32 + n * 16 + fr;
          float a1 = acc1[m][n][r], a3 = acc3[m][n][r];
          float hv = (a1 / (1.0f + __expf(-a1))) * a3;
          hf[(size_t)p * INTERN + col] =
              __builtin_bit_cast(unsigned short, (_Float16)hv);
        }
      }
}

// ----------------------------------------------------- GEMM2: h @ w2, out ---
__global__ __launch_bounds__(NTG, 4) void gemm2_kernel(
    const unsigned short* __restrict__ w2f, const int* __restrict__ offs,
    const int* __restrict__ pairs, const unsigned short* __restrict__ hf,
    float* __restrict__ out) {
  __shared__ __align__(16) unsigned short At[BM * BK];
  __shared__ __align__(16) unsigned short Bt[BN * BK];

  const int lid = xcd_swz((int)blockIdx.x, MAXRT * NT2);
  const int rt = lid % MAXRT, nt = lid / MAXRT;
  int e, row0, row_end;
  if (!find_tile(offs, rt, e, row0, row_end)) return;
  const int n0 = nt * BN;
  const int t = threadIdx.x;
  const int ln = t & 63;
  const int wv = t >> 6;
  const int wm = wv >> 2, wn = wv & 3;
  const int fr = ln & 15, fg = ln >> 4;
  const int sr = ln >> 3, sc = ln & 7;
  const int sw = (sc ^ sr) * 8;

  size_t aA[2], aB[2];
#pragma unroll
  for (int c = 0; c < 2; ++c) {
    int row = wv * 16 + c * 8 + sr;
    int p = row0 + row;
    int ar = (p < row_end) ? p : row0;
    aA[c] = (size_t)ar * INTERN + sw;
    aB[c] = ((size_t)e * DIMK + n0 + row) * INTERN + sw;
  }

  f32x4 acc[4][2] = {};

  for (int k0 = 0; k0 < INTERN; k0 += BK) {
#pragma unroll
    for (int c = 0; c < 2; ++c)
      gl_lds16(hf + aA[c] + k0, &At[(wv * 16 + c * 8) * BK]);
#pragma unroll
    for (int c = 0; c < 2; ++c)
      gl_lds16(w2f + aB[c] + k0, &Bt[(wv * 16 + c * 8) * BK]);
    __syncthreads();

#pragma unroll
    for (int kk = 0; kk < 2; ++kk) {
      half8 ah[4];
#pragma unroll
      for (int m = 0; m < 4; ++m) {
        int row = wm * 64 + m * 16 + fr;
        ah[m] = *reinterpret_cast<const half8*>(
            &At[row * BK + (((kk * 4 + fg) ^ (fr & 7)) * 8)]);
      }
#pragma unroll
      for (int n = 0; n < 2; ++n) {
        int row = wn * 32 + n * 16 + fr;
        half8 b = *reinterpret_cast<const half8*>(
            &Bt[row * BK + (((kk * 4 + fg) ^ (fr & 7)) * 8)]);
#pragma unroll
        for (int m = 0; m < 4; ++m)
          acc[m][n] = MFMAF16(ah[m], b, acc[m][n]);
      }
    }
    __syncthreads();
  }

#pragma unroll
  for (int m = 0; m < 4; ++m)
#pragma unroll
    for (int n = 0; n < 2; ++n)
#pragma unroll
      for (int r = 0; r < 4; ++r) {
        int p = row0 + wm * 64 + m * 16 + fg * 4 + r;
        if (p < row_end) {
          int orow = pairs[p];
          out[(size_t)orow * DIMK + n0 + wn * 32 + n * 16 + fr] = acc[m][n][r];
        }
      }
}

// ------------------------------------------------------------------ launch ---
extern "C" void kernel_launch(void* const* d_in, const int* in_sizes, int n_in,
                              void* d_out, int out_size, void* d_ws, size_t ws_size,
                              hipStream_t stream) {
  const float* x  = (const float*)d_in[0];
  const int*   ei = (const int*)d_in[1];
  const float* w1 = (const float*)d_in[2];
  const float* w2 = (const float*)d_in[3];
  const float* w3 = (const float*)d_in[4];
  float* out = (float*)d_out;

  char* ws = (char*)d_ws;
  int* offs  = (int*)ws;                       // 9 ints
  int* pairs = (int*)(ws + 256);               // 8192 ints

  const size_t sz_x = (size_t)TTOK * DIMK;           // 4.19M
  const size_t sz_w = (size_t)NEXP * INTERN * DIMK;  // 11.53M
  size_t off = 65536;
  unsigned short* x_f  = (unsigned short*)(ws + off); off += sz_x * 2;
  unsigned short* w1_f = (unsigned short*)(ws + off); off += sz_w * 2;
  unsigned short* w3_f = (unsigned short*)(ws + off); off += sz_w * 2;
  unsigned short* w2_f = (unsigned short*)(ws + off); off += sz_w * 2;
  unsigned short* h_f  = (unsigned short*)(ws + off);   // ~101 MB total

  route_kernel<<<1, NTH, 0, stream>>>(ei, offs, pairs);
  convert_all_kernel<<<4096, NTH, 0, stream>>>(x, w1, w3, w2, x_f, w1_f, w3_f, w2_f);
  gemm1_kernel<<<MAXRT * NT1, NTG, 0, stream>>>(x_f, w1_f, w3_f, offs, pairs, h_f);
  gemm2_kernel<<<MAXRT * NT2, NTG, 0, stream>>>(w2_f, offs, pairs, h_f, out);
}

// Round 10
// 301.431 us; speedup vs baseline: 2.1771x; 1.0190x over previous
//
#include <hip/hip_runtime.h>

#define TTOK   4096
#define DIMK   1024
#define NEXP   8
#define INTERN 1408
#define NPAIRS 8192   // TTOK * TOPK

#define BM  128
#define BN  128
#define BK  64
#define NTH 256       // prep block size
#define NTG 512       // GEMM block size: 8 waves, 2x4 wave grid
#define MAXRT (NPAIRS / BM + NEXP - 1)   // 71 worst-case row tiles
#define NT1  (INTERN / BN)               // 11 n-tiles gemm1
#define NT2  (DIMK / BN)                 // 8 n-tiles gemm2

#define CVTBLKS 4096                     // convert blocks; +1 block does routing
#define N8X (TTOK * DIMK / 8)            // 8-float units per array
#define N8W (NEXP * INTERN * DIMK / 8)

typedef __attribute__((ext_vector_type(8))) _Float16 half8;
typedef __attribute__((ext_vector_type(2))) _Float16 half2v;
typedef __attribute__((ext_vector_type(4))) float f32x4;

#define MFMAF16(a, b, c) __builtin_amdgcn_mfma_f32_16x16x32_f16((a), (b), (c), 0, 0, 0)

// async global->LDS, 16B/lane. LDS dest = wave-uniform base + lane*16 (linear);
// swizzle lives in the per-lane GLOBAL source address (m173 pattern).
__device__ __forceinline__ void gl_lds16(const void* g, void* l) {
  __builtin_amdgcn_global_load_lds(
      (const __attribute__((address_space(1))) void*)g,
      (__attribute__((address_space(3))) void*)l, 16, 0, 0);
}

// bijective XCD chunk swizzle (m204)
__device__ __forceinline__ int xcd_swz(int orig, int G) {
  int q = G >> 3, r = G & 7, x = orig & 7, p = orig >> 3;
  return (x < r ? x * (q + 1) : r * (q + 1) + (x - r) * q) + p;
}

// ------------------- fused prep: fp32->fp16 convert (+1 block does routing) ---
// Branchless per-array grid-stride loops: 8 floats/iter (2x f32x4 load, one
// 16B store) so the compiler can unroll & keep multiple loads in flight.
__device__ __forceinline__ void cvt8(const float* __restrict__ src,
                                     unsigned short* __restrict__ dst,
                                     int n8, int tid, int stride) {
  const f32x4* s4 = reinterpret_cast<const f32x4*>(src);
  uint4* d4 = reinterpret_cast<uint4*>(dst);
  for (int i = tid; i < n8; i += stride) {
    f32x4 a = s4[2 * i], b = s4[2 * i + 1];
    uint4 o;
    o.x = __builtin_bit_cast(unsigned int, __builtin_amdgcn_cvt_pkrtz(a[0], a[1]));
    o.y = __builtin_bit_cast(unsigned int, __builtin_amdgcn_cvt_pkrtz(a[2], a[3]));
    o.z = __builtin_bit_cast(unsigned int, __builtin_amdgcn_cvt_pkrtz(b[0], b[1]));
    o.w = __builtin_bit_cast(unsigned int, __builtin_amdgcn_cvt_pkrtz(b[2], b[3]));
    d4[i] = o;
  }
}

__global__ __launch_bounds__(NTH) void prep_kernel(
    const float* __restrict__ x, const float* __restrict__ w1,
    const float* __restrict__ w3, const float* __restrict__ w2,
    unsigned short* __restrict__ xf, unsigned short* __restrict__ w1f,
    unsigned short* __restrict__ w3f, unsigned short* __restrict__ w2f,
    const int* __restrict__ ei, int* __restrict__ offs, int* __restrict__ pairs) {
  const int t = threadIdx.x;

  if (blockIdx.x == CVTBLKS) {
    // ---- routing block (runs concurrently with the convert blocks) ----
    __shared__ int cnt[NEXP], base[NEXP], cur[NEXP], mode;
    if (t == 0) mode = 0;
    if (t < NEXP) cnt[t] = 0;
    __syncthreads();
    // width probe: odd 32-bit words all-zero => int64 input, else int32
    int any = 0;
    for (int i = t; i < NPAIRS / 2; i += NTH) any |= ei[2 * i + 1];
    if (any) atomicOr(&mode, 1);
    __syncthreads();
    const int m32 = mode;
    for (int i = t; i < NPAIRS; i += NTH) {
      int e = (m32 ? ei[i] : ei[2 * i]) & (NEXP - 1);
      atomicAdd(&cnt[e], 1);
    }
    __syncthreads();
    if (t == 0) {
      int s = 0;
      for (int e = 0; e < NEXP; ++e) { base[e] = s; offs[e] = s; s += cnt[e]; }
      offs[NEXP] = s;
    }
    __syncthreads();
    if (t < NEXP) cur[t] = base[t];
    __syncthreads();
    for (int i = t; i < NPAIRS; i += NTH) {
      int e = (m32 ? ei[i] : ei[2 * i]) & (NEXP - 1);
      int p = atomicAdd(&cur[e], 1);
      pairs[p] = i;   // pair id: token = i>>1, out row = i
    }
    return;
  }

  const int tid = blockIdx.x * NTH + t;
  const int stride = CVTBLKS * NTH;
  cvt8(x,  xf,  N8X, tid, stride);
  cvt8(w1, w1f, N8W, tid, stride);
  cvt8(w3, w3f, N8W, tid, stride);
  cvt8(w2, w2f, N8W, tid, stride);
}

// ------------------------------------------------------------ tile lookup ---
__device__ __forceinline__ bool find_tile(const int* __restrict__ offs, int rt,
                                          int &e, int &row0, int &row_end) {
  int cum = 0;
  for (int i = 0; i < NEXP; ++i) {
    int b = offs[i], en = offs[i + 1];
    int nt = (en - b + BM - 1) / BM;
    if (rt < cum + nt) { e = i; row0 = b + (rt - cum) * BM; row_end = en; return true; }
    cum += nt;
  }
  return false;
}

// -------------------------------------------------- GEMM1: x @ w1/w3, SiLU ---
// 512 threads = 8 waves as 2(wm) x 4(wn); per wave 64x32 out per matrix.
__global__ __launch_bounds__(NTG, 4) void gemm1_kernel(
    const unsigned short* __restrict__ xf, const unsigned short* __restrict__ w1f,
    const unsigned short* __restrict__ w3f, const int* __restrict__ offs,
    const int* __restrict__ pairs, unsigned short* __restrict__ hf) {
  // flat [row][BK] fp16 tiles, 16KB each. LDS row r chunk c holds global
  // chunk c^(r&7) (pre-swizzled source, swizzled read -> 0 bank conflicts, R8-verified)
  __shared__ __align__(16) unsigned short At[BM * BK];
  __shared__ __align__(16) unsigned short B1t[BN * BK];
  __shared__ __align__(16) unsigned short B3t[BN * BK];

  const int lid = xcd_swz((int)blockIdx.x, MAXRT * NT1);
  const int rt = lid % MAXRT, nt = lid / MAXRT;   // rt fastest: XCD sweeps row
  int e, row0, row_end;                           // tiles vs L2-hot W slice
  if (!find_tile(offs, rt, e, row0, row_end)) return;
  const int n0 = nt * BN;
  const int t = threadIdx.x;
  const int ln = t & 63;
  const int wv = t >> 6;                 // wave 0..7
  const int wm = wv >> 2, wn = wv & 3;   // 2x4 wave grid over 128x128 out
  const int fr = ln & 15, fg = ln >> 4;
  const int sr = ln >> 3, sc = ln & 7;   // staging row-in-8 / chunk
  const int sw = (sc ^ sr) * 8;          // swizzled source chunk offset (halfs)

  size_t aA[2], aB[2];
#pragma unroll
  for (int c = 0; c < 2; ++c) {
    int row = wv * 16 + c * 8 + sr;      // 0..127
    int p = row0 + row;
    int tok = ((p < row_end) ? pairs[p] : pairs[row0]) >> 1;
    aA[c] = (size_t)tok * DIMK + sw;
    aB[c] = ((size_t)e * INTERN + n0 + row) * DIMK + sw;
  }

  f32x4 acc1[4][2] = {};
  f32x4 acc3[4][2] = {};

  for (int k0 = 0; k0 < DIMK; k0 += BK) {
#pragma unroll
    for (int c = 0; c < 2; ++c)
      gl_lds16(xf + aA[c] + k0, &At[(wv * 16 + c * 8) * BK]);
#pragma unroll
    for (int c = 0; c < 2; ++c)
      gl_lds16(w1f + aB[c] + k0, &B1t[(wv * 16 + c * 8) * BK]);
#pragma unroll
    for (int c = 0; c < 2; ++c)
      gl_lds16(w3f + aB[c] + k0, &B3t[(wv * 16 + c * 8) * BK]);
    __syncthreads();   // compiler drains vmcnt before s_barrier

#pragma unroll
    for (int kk = 0; kk < 2; ++kk) {
      half8 ah[4];
#pragma unroll
      for (int m = 0; m < 4; ++m) {
        int row = wm * 64 + m * 16 + fr;
        ah[m] = *reinterpret_cast<const half8*>(
            &At[row * BK + (((kk * 4 + fg) ^ (fr & 7)) * 8)]);
      }
#pragma unroll
      for (int n = 0; n < 2; ++n) {
        int row = wn * 32 + n * 16 + fr;
        int bo = row * BK + (((kk * 4 + fg) ^ (fr & 7)) * 8);
        half8 b1 = *reinterpret_cast<const half8*>(&B1t[bo]);
        half8 b3 = *reinterpret_cast<const half8*>(&B3t[bo]);
#pragma unroll
        for (int m = 0; m < 4; ++m) {
          acc1[m][n] = MFMAF16(ah[m], b1, acc1[m][n]);
          acc3[m][n] = MFMAF16(ah[m], b3, acc3[m][n]);
        }
      }
    }
    __syncthreads();
  }

  // ---- epilogue: h = silu(x1) * x3 -> fp16 ----
#pragma unroll
  for (int m = 0; m < 4; ++m)
#pragma unroll
    for (int n = 0; n < 2; ++n)
#pragma unroll
      for (int r = 0; r < 4; ++r) {
        int p = row0 + wm * 64 + m * 16 + fg * 4 + r;
        if (p < row_end) {
          int col = n0 + wn * 32 + n * 16 + fr;
          float a1 = acc1[m][n][r], a3 = acc3[m][n][r];
          float hv = (a1 / (1.0f + __expf(-a1))) * a3;
          hf[(size_t)p * INTERN + col] =
              __builtin_bit_cast(unsigned short, (_Float16)hv);
        }
      }
}

// ----------------------------------------------------- GEMM2: h @ w2, out ---
__global__ __launch_bounds__(NTG, 4) void gemm2_kernel(
    const unsigned short* __restrict__ w2f, const int* __restrict__ offs,
    const int* __restrict__ pairs, const unsigned short* __restrict__ hf,
    float* __restrict__ out) {
  __shared__ __align__(16) unsigned short At[BM * BK];
  __shared__ __align__(16) unsigned short Bt[BN * BK];

  const int lid = xcd_swz((int)blockIdx.x, MAXRT * NT2);
  const int rt = lid % MAXRT, nt = lid / MAXRT;
  int e, row0, row_end;
  if (!find_tile(offs, rt, e, row0, row_end)) return;
  const int n0 = nt * BN;
  const int t = threadIdx.x;
  const int ln = t & 63;
  const int wv = t >> 6;
  const int wm = wv >> 2, wn = wv & 3;
  const int fr = ln & 15, fg = ln >> 4;
  const int sr = ln >> 3, sc = ln & 7;
  const int sw = (sc ^ sr) * 8;

  size_t aA[2], aB[2];
#pragma unroll
  for (int c = 0; c < 2; ++c) {
    int row = wv * 16 + c * 8 + sr;
    int p = row0 + row;
    int ar = (p < row_end) ? p : row0;
    aA[c] = (size_t)ar * INTERN + sw;
    aB[c] = ((size_t)e * DIMK + n0 + row) * INTERN + sw;
  }

  f32x4 acc[4][2] = {};

  for (int k0 = 0; k0 < INTERN; k0 += BK) {
#pragma unroll
    for (int c = 0; c < 2; ++c)
      gl_lds16(hf + aA[c] + k0, &At[(wv * 16 + c * 8) * BK]);
#pragma unroll
    for (int c = 0; c < 2; ++c)
      gl_lds16(w2f + aB[c] + k0, &Bt[(wv * 16 + c * 8) * BK]);
    __syncthreads();

#pragma unroll
    for (int kk = 0; kk < 2; ++kk) {
      half8 ah[4];
#pragma unroll
      for (int m = 0; m < 4; ++m) {
        int row = wm * 64 + m * 16 + fr;
        ah[m] = *reinterpret_cast<const half8*>(
            &At[row * BK + (((kk * 4 + fg) ^ (fr & 7)) * 8)]);
      }
#pragma unroll
      for (int n = 0; n < 2; ++n) {
        int row = wn * 32 + n * 16 + fr;
        half8 b = *reinterpret_cast<const half8*>(
            &Bt[row * BK + (((kk * 4 + fg) ^ (fr & 7)) * 8)]);
#pragma unroll
        for (int m = 0; m < 4; ++m)
          acc[m][n] = MFMAF16(ah[m], b, acc[m][n]);
      }
    }
    __syncthreads();
  }

#pragma unroll
  for (int m = 0; m < 4; ++m)
#pragma unroll
    for (int n = 0; n < 2; ++n)
#pragma unroll
      for (int r = 0; r < 4; ++r) {
        int p = row0 + wm * 64 + m * 16 + fg * 4 + r;
        if (p < row_end) {
          int orow = pairs[p];
          out[(size_t)orow * DIMK + n0 + wn * 32 + n * 16 + fr] = acc[m][n][r];
        }
      }
}

// ------------------------------------------------------------------ launch ---
extern "C" void kernel_launch(void* const* d_in, const int* in_sizes, int n_in,
                              void* d_out, int out_size, void* d_ws, size_t ws_size,
                              hipStream_t stream) {
  const float* x  = (const float*)d_in[0];
  const int*   ei = (const int*)d_in[1];
  const float* w1 = (const float*)d_in[2];
  const float* w2 = (const float*)d_in[3];
  const float* w3 = (const float*)d_in[4];
  float* out = (float*)d_out;

  char* ws = (char*)d_ws;
  int* offs  = (int*)ws;                       // 9 ints
  int* pairs = (int*)(ws + 256);               // 8192 ints

  const size_t sz_x = (size_t)TTOK * DIMK;           // 4.19M
  const size_t sz_w = (size_t)NEXP * INTERN * DIMK;  // 11.53M
  size_t off = 65536;
  unsigned short* x_f  = (unsigned short*)(ws + off); off += sz_x * 2;
  unsigned short* w1_f = (unsigned short*)(ws + off); off += sz_w * 2;
  unsigned short* w3_f = (unsigned short*)(ws + off); off += sz_w * 2;
  unsigned short* w2_f = (unsigned short*)(ws + off); off += sz_w * 2;
  unsigned short* h_f  = (unsigned short*)(ws + off);   // ~101 MB total

  prep_kernel<<<CVTBLKS + 1, NTH, 0, stream>>>(
      x, w1, w3, w2, x_f, w1_f, w3_f, w2_f, ei, offs, pairs);
  gemm1_kernel<<<MAXRT * NT1, NTG, 0, stream>>>(x_f, w1_f, w3_f, offs, pairs, h_f);
  gemm2_kernel<<<MAXRT * NT2, NTG, 0, stream>>>(w2_f, offs, pairs, h_f, out);
}